// Round 1
// 353.645 us; speedup vs baseline: 1.1086x; 1.1086x over previous
//
#include <hip/hip_runtime.h>
#include <hip/hip_bf16.h>
#include <stdint.h>

// Problem constants
#define BB 4
#define TT 2048
#define DD 1024
#define HH 16
#define HDD 64
// derived
#define M1 (BB*TT)      // 8192 rows
#define N1 (3*DD)       // 3072
#define KDIM DD         // 1024

typedef __attribute__((ext_vector_type(8))) short short8;   // 8 bf16 MFMA operand
typedef __attribute__((ext_vector_type(4))) float f32x4;

#if __has_builtin(__builtin_amdgcn_exp2f)
#define EXP2(x) __builtin_amdgcn_exp2f(x)
#else
#define EXP2(x) exp2f(x)
#endif

// async global->LDS, 16B per lane (global_load_lds_dwordx4)
#define GLOAD_LDS16(gp, lp) \
    __builtin_amdgcn_global_load_lds( \
        (const __attribute__((address_space(1))) void*)(gp), \
        (__attribute__((address_space(3))) void*)(lp), 16, 0, 0)

__device__ __forceinline__ float bf2f(unsigned short u) {
    union { uint32_t u32; float f; } c; c.u32 = ((uint32_t)u) << 16; return c.f;
}
__device__ __forceinline__ unsigned short f2bf(float f) {
    union { float f; uint32_t u32; } c; c.f = f;
    uint32_t u = c.u32;
    return (unsigned short)((u + 0x7FFFu + ((u >> 16) & 1u)) >> 16);  // RNE
}

// DPP row_ror rotate-reduce within the 16-lane DPP row (= one quad's l16 span).
// VALU-only — replaces __shfl_xor(...,16) which compiles to ds_swizzle (LDS pipe).
template <int CTRL>
__device__ __forceinline__ float dpp_ror(float x) {
    union { float f; int i; } u, r;
    u.f = x;
    r.i = __builtin_amdgcn_update_dpp(u.i, u.i, CTRL, 0xF, 0xF, false);
    return r.f;
}
__device__ __forceinline__ float red_max16(float x) {
    x = fmaxf(x, dpp_ror<0x128>(x));   // row_ror:8
    x = fmaxf(x, dpp_ror<0x124>(x));   // row_ror:4
    x = fmaxf(x, dpp_ror<0x122>(x));   // row_ror:2
    x = fmaxf(x, dpp_ror<0x121>(x));   // row_ror:1
    return x;
}
__device__ __forceinline__ float red_sum16(float x) {
    x += dpp_ror<0x128>(x);
    x += dpp_ror<0x124>(x);
    x += dpp_ror<0x122>(x);
    x += dpp_ror<0x121>(x);
    return x;
}

// ---------------- elementwise fp32 -> bf16 (x), 4 elems/thread ----------------
__global__ __launch_bounds__(256) void cvt_f32_bf16(
    const float* __restrict__ in, unsigned short* __restrict__ out, int n4)
{
    int i = blockIdx.x * 256 + threadIdx.x;
    if (i >= n4) return;
    float4 v = *(const float4*)&in[(size_t)i * 4];
    ushort4 o;
    o.x = f2bf(v.x); o.y = f2bf(v.y); o.z = f2bf(v.z); o.w = f2bf(v.w);
    *(ushort4*)&out[(size_t)i * 4] = o;
}

// ---------------- transpose+convert: in fp32 [R][C] -> out bf16 [C][R] ----------------
__global__ __launch_bounds__(256) void transpose_f32_bf16(
    const float* __restrict__ in, unsigned short* __restrict__ out,
    int R, int C)
{
    __shared__ unsigned short tile[32][33];
    int bx = blockIdx.x;
    int by = blockIdx.y;
    int x = bx*32 + threadIdx.x;
    int y0 = by*32 + threadIdx.y;
    #pragma unroll
    for (int i = 0; i < 32; i += 8)
        tile[threadIdx.y + i][threadIdx.x] = f2bf(in[(size_t)(y0 + i)*C + x]);
    __syncthreads();
    int xo = by*32 + threadIdx.x;
    int yo = bx*32 + threadIdx.y;
    #pragma unroll
    for (int i = 0; i < 32; i += 8)
        out[(size_t)(yo + i)*R + xo] = tile[threadIdx.x][threadIdx.y + i];
}

// ---------------- MFMA bf16 GEMM ----------------
// MODE 1: f32 C[M][N]
// MODE 2: QKV-split — n<2048 -> bf16 QK[M][2048]; n>=2048 -> V transposed via
//         LDS to VT[((b*16+h)*64+d)][2048]+t with fully-coalesced 16B stores.
// Staging via global_load_lds width=16 (m97 pattern).
#define TSTR 132
template <int MODE>
__global__ __launch_bounds__(256) void gemm_bf16_mfma(
    const unsigned short* __restrict__ A, const unsigned short* __restrict__ BT,
    const float* __restrict__ bias, void* __restrict__ Cout, void* __restrict__ Cout2,
    int M, int N, int K)
{
    constexpr int SHSZ = (MODE == 2) ? 128*TSTR : 128*64;
    __shared__ __align__(16) unsigned short Sh[SHSZ];
    unsigned short* As = Sh;            // 128*32 shorts
    unsigned short* Bs = Sh + 128*32;   // 128*32 shorts
    const int tid  = threadIdx.x;
    const int lane = tid & 63;
    const int wave = tid >> 6;
    const int wm = wave >> 1, wn = wave & 1;
    const int quad = lane >> 4, l16 = lane & 15;
    const int m0 = blockIdx.y * 128, n0 = blockIdx.x * 128;

    f32x4 acc[4][4] = {};

    const int nk = K >> 5;
    for (int kt = 0; kt < nk; ++kt) {
        const int k0 = kt << 5;
        __syncthreads();
        #pragma unroll
        for (int h = 0; h < 2; ++h) {
            int c = tid + h*256;
            int row = c >> 2, seg = c & 3;
            GLOAD_LDS16(&A[(size_t)(m0 + row)*K + k0 + seg*8], &As[row*32 + seg*8]);
            GLOAD_LDS16(&BT[(size_t)(n0 + row)*K + k0 + seg*8], &Bs[row*32 + seg*8]);
        }
        __syncthreads();   // compiler drains vmcnt before barrier
        short8 af[4], bf[4];
        #pragma unroll
        for (int mi = 0; mi < 4; ++mi)
            af[mi] = *(short8*)&As[(wm*64 + mi*16 + l16)*32 + quad*8];
        #pragma unroll
        for (int ni = 0; ni < 4; ++ni)
            bf[ni] = *(short8*)&Bs[(wn*64 + ni*16 + l16)*32 + quad*8];
        #pragma unroll
        for (int mi = 0; mi < 4; ++mi)
            #pragma unroll
            for (int ni = 0; ni < 4; ++ni)
                acc[mi][ni] = __builtin_amdgcn_mfma_f32_16x16x32_bf16(
                    af[mi], bf[ni], acc[mi][ni], 0, 0, 0);
    }

    if (MODE == 2 && n0 >= 2048) {
        // V third: transpose through LDS, then coalesced 16B stores to VT[d-row][t]
        __syncthreads();   // all As/Bs reads done before aliasing Sh
        #pragma unroll
        for (int ni = 0; ni < 4; ++ni) {
            int nl = wn*64 + ni*16 + l16;        // local n 0..127
            float bv = bias[n0 + nl];
            #pragma unroll
            for (int mi = 0; mi < 4; ++mi) {
                ushort4 pk;
                pk.x = f2bf(acc[mi][ni][0] + bv);
                pk.y = f2bf(acc[mi][ni][1] + bv);
                pk.z = f2bf(acc[mi][ni][2] + bv);
                pk.w = f2bf(acc[mi][ni][3] + bv);
                *(ushort4*)&Sh[nl*TSTR + wm*64 + mi*16 + quad*4] = pk;
            }
        }
        __syncthreads();
        const int bb = m0 >> 11, t0 = m0 & 2047;
        #pragma unroll
        for (int p = 0; p < 8; ++p) {
            int c = tid + p*256;
            int row = c >> 4, ch = c & 15;       // row: local n, ch: 8-short chunk of m
            int nv = n0 + row - 2048;            // 0..1023
            int hv = nv >> 6, dv = nv & 63;
            *(uint4*)&((unsigned short*)Cout2)[((size_t)((bb*16 + hv)*64 + dv))*2048 + t0 + ch*8] =
                *(uint4*)&Sh[row*TSTR + ch*8];
        }
        return;
    }

    const int cstride = (MODE == 2) ? 2048 : N;
    #pragma unroll
    for (int ni = 0; ni < 4; ++ni) {
        int n = n0 + wn*64 + ni*16 + l16;
        float bv = bias[n];
        #pragma unroll
        for (int mi = 0; mi < 4; ++mi) {
            #pragma unroll
            for (int r = 0; r < 4; ++r) {
                int m = m0 + wm*64 + mi*16 + quad*4 + r;
                float val = acc[mi][ni][r] + bv;
                if (MODE == 1)
                    ((float*)Cout)[(size_t)m*cstride + n] = val;
                else
                    ((unsigned short*)Cout)[(size_t)m*cstride + n] = f2bf(val);
            }
        }
    }
}

// ---------------- MFMA flash attention: 4-wave block, LDS-staged K/V ----------------
// Block = 4 waves x 32 q-rows = 128 q-rows of one (b,h). Previous round was
// 1-wave blocks with per-wave global K/V frag loads: MfmaUtil 7.9%, VALUBusy 25%,
// ~10x chain-stall factor (latency-bound). This round:
//  - K/V 64x64 bf16 tiles (8 KB each) staged to LDS via global_load_lds dwordx4,
//    double-buffered, 2-phase pipeline: STAGE(next) -> compute(cur) ->
//    s_waitcnt vmcnt(0) -> s_barrier (raw; __syncthreads would drain early).
//    Loads shared by 4 waves, latency hidden under compute.
//  - LDS layout XOR-swizzle (16B chunk ^= row&7) applied on the GLOBAL source
//    address (gload_lds dest must be linear; rule: both-sides-or-neither),
//    matching XOR on ds_read -> <=2-way bank conflict (free) instead of 16-way.
//  - Softmax row-reductions via DPP row_ror rotate-reduce (VALU pipe) instead of
//    __shfl_xor -> ds_swizzle (removes ~64 LDS-pipe ops per wave-iter).
// Grid 1024 blocks: xcd = i&7 pins each (b,h) group to one XCD (L2 locality);
// long causal rows (high qc) dispatched first for load balance.
#define PST 72
__global__ __launch_bounds__(256, 3) void attn_mfma(
    const unsigned short* __restrict__ QK, const unsigned short* __restrict__ VT,
    unsigned short* __restrict__ Y)
{
    // LDS: K dbuf 2x4096 shorts, V dbuf 2x4096 shorts, P 4 waves x 32 x PST
    __shared__ __align__(16) unsigned short Sh[16384 + 4*32*PST];

    const int tid  = threadIdx.x;
    const int lane = tid & 63;
    const int wave = tid >> 6;
    const int quad = lane >> 4, l16 = lane & 15;

    const int i = blockIdx.x;
    const int xcd = i & 7, j = i >> 3;
    const int qc = 15 - (j & 15);              // q-chunk, long rows first
    const int bh = xcd + 8*(j >> 4);
    const int b = bh >> 4, h = bh & 15;
    const int q0b = qc * 128;
    const int q0w = q0b + wave*32;
    const size_t qkbase = (size_t)(b*TT) * 2048;
    const size_t vbase  = (size_t)(bh*64) * 2048;
    const int qcol = h*64, kcol = 1024 + h*64;
    const float C2 = 0.18033688011112042f;   // (1/sqrt(64)) * log2(e)

    unsigned short* Pw = &Sh[16384 + wave*(32*PST)];

    // Q fragments straight from global (held for the whole loop)
    short8 aq[2][2];
    #pragma unroll
    for (int mt = 0; mt < 2; ++mt)
        #pragma unroll
        for (int kk = 0; kk < 2; ++kk)
            aq[mt][kk] = *(const short8*)&QK[qkbase + (size_t)(q0w + mt*16 + l16)*2048
                                            + qcol + kk*32 + quad*8];

    f32x4 o[2][4] = {};
    float mold[2][4], lsum[2][4];
    #pragma unroll
    for (int mt = 0; mt < 2; ++mt)
        #pragma unroll
        for (int r = 0; r < 4; ++r) { mold[mt][r] = -3.0e38f; lsum[mt][r] = 0.0f; }

    const int nkt = 2*qc + 2;                  // block-uniform k-tile count

    // stage K/V tile kt into buffer buf; dest linear in lane, source pre-swizzled
    auto STAGE = [&](int buf, int kt) {
        const int k0 = kt << 6;
        unsigned short* Kb = &Sh[buf*4096];
        unsigned short* Vb = &Sh[8192 + buf*4096];
        #pragma unroll
        for (int p = 0; p < 2; ++p) {
            int c = p*256 + tid;               // 16B chunk index, linear in lane
            int r = c >> 3;
            int ch = (c & 7) ^ (r & 7);        // source chunk (inverse swizzle)
            GLOAD_LDS16(&QK[qkbase + (size_t)(k0 + r)*2048 + kcol + ch*8], &Kb[c*8]);
        }
        #pragma unroll
        for (int p = 0; p < 2; ++p) {
            int c = p*256 + tid;
            int r = c >> 3;                    // r = head-dim row of VT
            int ch = (c & 7) ^ (r & 7);
            GLOAD_LDS16(&VT[vbase + (size_t)r*2048 + k0 + ch*8], &Vb[c*8]);
        }
    };

    STAGE(0, 0);
    asm volatile("s_waitcnt vmcnt(0)" ::: "memory");
    __builtin_amdgcn_s_barrier();

    int cur = 0;
    for (int kt = 0; kt < nkt; ++kt) {
        const int k0 = kt * 64;
        if (kt + 1 < nkt) STAGE(cur ^ 1, kt + 1);   // async prefetch next tile

        if (k0 <= q0w + 31) {                  // wave-uniform causal activity guard
            const unsigned short* Kb = &Sh[cur*4096];
            const unsigned short* Vb = &Sh[8192 + cur*4096];

            // ---- S = Q K^T from LDS (swizzled reads)
            f32x4 s[2][4];
            #pragma unroll
            for (int nt = 0; nt < 4; ++nt) {
                if (k0 + nt*16 <= q0w + 31) {
                    f32x4 z = {};
                    s[0][nt] = z; s[1][nt] = z;
                    #pragma unroll
                    for (int kk = 0; kk < 2; ++kk) {
                        int r = nt*16 + l16;
                        short8 bk = *(const short8*)&Kb[r*64 + (((kk*4 + quad) ^ (r & 7))*8)];
                        s[0][nt] = __builtin_amdgcn_mfma_f32_16x16x32_bf16(aq[0][kk], bk, s[0][nt], 0, 0, 0);
                        s[1][nt] = __builtin_amdgcn_mfma_f32_16x16x32_bf16(aq[1][kk], bk, s[1][nt], 0, 0, 0);
                    }
                } else {
                    #pragma unroll
                    for (int r = 0; r < 4; ++r) { s[0][nt][r] = -3.0e38f; s[1][nt][r] = -3.0e38f; }
                }
            }

            // ---- element causal mask (straddling tiles only)
            if (k0 + 63 > q0w) {
                #pragma unroll
                for (int mt = 0; mt < 2; ++mt)
                    #pragma unroll
                    for (int nt = 0; nt < 4; ++nt)
                        #pragma unroll
                        for (int r = 0; r < 4; ++r) {
                            int kg = k0 + nt*16 + l16;
                            int qg = q0w + mt*16 + quad*4 + r;
                            if (kg > qg) s[mt][nt][r] = -3.0e38f;
                        }
            }

            // ---- online softmax (exp2 domain), DPP reductions
            float m2n[2][4], al[2][4];
            #pragma unroll
            for (int mt = 0; mt < 2; ++mt)
                #pragma unroll
                for (int r = 0; r < 4; ++r) {
                    float rm = fmaxf(fmaxf(s[mt][0][r], s[mt][1][r]),
                                     fmaxf(s[mt][2][r], s[mt][3][r]));
                    rm = red_max16(rm);
                    float m2 = fmaxf(mold[mt][r], rm * C2);
                    al[mt][r]  = EXP2(mold[mt][r] - m2);
                    m2n[mt][r] = m2;
                }
            float rs[2][4] = {};
            #pragma unroll
            for (int mt = 0; mt < 2; ++mt)
                #pragma unroll
                for (int nt = 0; nt < 4; ++nt)
                    #pragma unroll
                    for (int r = 0; r < 4; ++r) {
                        float p = EXP2(fmaf(s[mt][nt][r], C2, -m2n[mt][r]));
                        s[mt][nt][r] = p;
                        rs[mt][r] += p;
                    }
            #pragma unroll
            for (int mt = 0; mt < 2; ++mt)
                #pragma unroll
                for (int r = 0; r < 4; ++r) {
                    float t = red_sum16(rs[mt][r]);
                    lsum[mt][r] = lsum[mt][r]*al[mt][r] + t;
                    mold[mt][r] = m2n[mt][r];
                }

            // ---- P -> LDS (wave-private buffer; same-wave RAW, no barrier)
            #pragma unroll
            for (int mt = 0; mt < 2; ++mt)
                #pragma unroll
                for (int nt = 0; nt < 4; ++nt)
                    #pragma unroll
                    for (int r = 0; r < 4; ++r) {
                        union { float f; uint32_t u; } c; c.f = s[mt][nt][r];
                        Pw[(mt*16 + quad*4 + r)*PST + nt*16 + l16] =
                            (unsigned short)((c.u + 0x8000u) >> 16);
                    }

            // ---- O = O*alpha + P V   (V frags from LDS, loaded late: lower VGPR peak)
            #pragma unroll
            for (int mt = 0; mt < 2; ++mt)
                #pragma unroll
                for (int dt = 0; dt < 4; ++dt)
                    #pragma unroll
                    for (int r = 0; r < 4; ++r)
                        o[mt][dt][r] *= al[mt][r];
            short8 bv[2][4];
            #pragma unroll
            for (int kk = 0; kk < 2; ++kk)
                #pragma unroll
                for (int dt = 0; dt < 4; ++dt) {
                    int r = dt*16 + l16;
                    bv[kk][dt] = *(const short8*)&Vb[r*64 + (((kk*4 + quad) ^ (r & 7))*8)];
                }
            #pragma unroll
            for (int kk = 0; kk < 2; ++kk) {
                short8 ap0 = *(short8*)&Pw[(     l16)*PST + kk*32 + quad*8];
                short8 ap1 = *(short8*)&Pw[(16 + l16)*PST + kk*32 + quad*8];
                #pragma unroll
                for (int dt = 0; dt < 4; ++dt) {
                    o[0][dt] = __builtin_amdgcn_mfma_f32_16x16x32_bf16(ap0, bv[kk][dt], o[0][dt], 0, 0, 0);
                    o[1][dt] = __builtin_amdgcn_mfma_f32_16x16x32_bf16(ap1, bv[kk][dt], o[1][dt], 0, 0, 0);
                }
            }
        }

        asm volatile("s_waitcnt vmcnt(0)" ::: "memory");  // next-tile stage landed
        __builtin_amdgcn_s_barrier();                     // all waves' stage + reads done
        cur ^= 1;
    }

    // ---- normalize + store (bf16 intermediate Y)
    #pragma unroll
    for (int mt = 0; mt < 2; ++mt)
        #pragma unroll
        for (int r = 0; r < 4; ++r) {
            float inv = 1.0f / lsum[mt][r];
            int t = q0w + mt*16 + quad*4 + r;
            #pragma unroll
            for (int dt = 0; dt < 4; ++dt)
                Y[((size_t)(b*TT + t))*DD + h*64 + dt*16 + l16] = f2bf(o[mt][dt][r] * inv);
        }
}

extern "C" void kernel_launch(void* const* d_in, const int* in_sizes, int n_in,
                              void* d_out, int out_size, void* d_ws, size_t ws_size,
                              hipStream_t stream)
{
    const float* x    = (const float*)d_in[0];   // [4,2048,1024] fp32
    // d_in[1] = causal_mask (int32) — causality implemented analytically, unused
    const float* wqkv = (const float*)d_in[2];   // [1024][3072] fp32
    const float* bqkv = (const float*)d_in[3];   // [3072] fp32
    const float* wout = (const float*)d_in[4];   // [1024][1024] fp32
    const float* bout = (const float*)d_in[5];   // [1024] fp32
    float* out = (float*)d_out;                  // [4,2048,1024] fp32

    char* ws = (char*)d_ws;
    unsigned short* Xb    = (unsigned short*)ws;                    // 16 MB
    unsigned short* WqkvT = (unsigned short*)(ws + 16777216);       // 6 MB
    unsigned short* WoutT = (unsigned short*)(ws + 23068672);       // 2 MB
    unsigned short* QK    = (unsigned short*)(ws + 25165824);       // 32 MB [M][2048]
    unsigned short* VTb   = (unsigned short*)(ws + 58720256);       // 16 MB [(bh*64+d)][2048]
    unsigned short* Ybuf  = (unsigned short*)(ws + 75497472);       // 16 MB

    cvt_f32_bf16<<<(M1*KDIM/4 + 255)/256, 256, 0, stream>>>(x, Xb, M1*KDIM/4);
    transpose_f32_bf16<<<dim3(N1/32, KDIM/32), dim3(32, 8), 0, stream>>>(wqkv, WqkvT, KDIM, N1);
    transpose_f32_bf16<<<dim3(DD/32, KDIM/32), dim3(32, 8), 0, stream>>>(wout, WoutT, KDIM, DD);
    gemm_bf16_mfma<2><<<dim3(N1/128, M1/128), 256, 0, stream>>>(Xb, WqkvT, bqkv, QK, VTb, M1, N1, KDIM);
    attn_mfma<<<dim3(1024), 256, 0, stream>>>(QK, VTb, Ybuf);
    gemm_bf16_mfma<1><<<dim3(DD/128, M1/128), 256, 0, stream>>>(Ybuf, WoutT, bout, out, nullptr, M1, DD, KDIM);
}